// Round 1
// baseline (79.259 us; speedup 1.0000x reference)
//
#include <hip/hip_runtime.h>

#define BSZ   64
#define NF    4
#define NCLS  4
#define PLO   256
#define PHI   16384
#define KN    9

__global__ __launch_bounds__(256) void rect_upsample_kernel(
    const float* __restrict__ x,         // (B, NF*PLO)
    const float* __restrict__ orog,      // (B, PHI, 2)
    const float* __restrict__ wmap,      // (NCLS, NF, PHI, KN, 3)
    const float* __restrict__ bias_low,  // (NCLS, NF, PLO)
    const float* __restrict__ bias_high, // (NCLS, NF, PHI)
    const float* __restrict__ bias_orog, // (NCLS, 2, PHI)
    const int*   __restrict__ cls_ids,   // (B,)
    const int*   __restrict__ nb,        // (PHI, KN)
    float* __restrict__ out)             // (B, NF, PHI)
{
    __shared__ float ylow[NF][PLO];

    const int b     = blockIdx.x >> 6;   // 64 p-chunks per batch
    const int chunk = blockIdx.x & 63;
    const int t     = threadIdx.x;
    const int cls   = cls_ids[b];

    // Stage y_low = x - bias_low[cls] for this batch (4 x 256 floats)
    #pragma unroll
    for (int f = 0; f < NF; ++f) {
        ylow[f][t] = x[b * (NF * PLO) + f * PLO + t]
                   - bias_low[(cls * NF + f) * PLO + t];
    }
    __syncthreads();

    const int p = chunk * 256 + t;

    // Gather neighbor info once (shared across the 4 features)
    int   lowi[KN];
    float yo0[KN], yo1[KN];
    #pragma unroll
    for (int k = 0; k < KN; ++k) {
        const int n = nb[p * KN + k];
        const int i = n >> 7;        // row in 128-grid
        const int j = n & 127;       // col in 128-grid
        lowi[k] = ((i >> 3) << 4) + (j >> 3);   // low-res cell index
        const float2 o = *reinterpret_cast<const float2*>(&orog[(size_t)(b * PHI + n) * 2]);
        yo0[k] = o.x - bias_orog[(cls * 2 + 0) * PHI + n];
        yo1[k] = o.y - bias_orog[(cls * 2 + 1) * PHI + n];
    }

    #pragma unroll
    for (int f = 0; f < NF; ++f) {
        const float* __restrict__ w = &wmap[(size_t)((cls * NF + f) * PHI + p) * (KN * 3)];
        float acc = bias_high[(cls * NF + f) * PHI + p];
        #pragma unroll
        for (int k = 0; k < KN; ++k) {
            const float yh = ylow[f][lowi[k]];
            acc += yh     * w[k * 3 + 0]
                 + yo0[k] * w[k * 3 + 1]
                 + yo1[k] * w[k * 3 + 2];
        }
        out[(size_t)(b * NF + f) * PHI + p] = acc;
    }
}

extern "C" void kernel_launch(void* const* d_in, const int* in_sizes, int n_in,
                              void* d_out, int out_size, void* d_ws, size_t ws_size,
                              hipStream_t stream) {
    const float* x         = (const float*)d_in[0];
    const float* orog      = (const float*)d_in[1];
    const float* wmap      = (const float*)d_in[2];
    const float* bias_low  = (const float*)d_in[3];
    const float* bias_high = (const float*)d_in[4];
    const float* bias_orog = (const float*)d_in[5];
    const int*   cls_ids   = (const int*)d_in[6];
    const int*   nb        = (const int*)d_in[7];
    float* out = (float*)d_out;

    // grid: 64 batches x 64 chunks of 256 high-res pixels
    dim3 grid(BSZ * (PHI / 256));
    dim3 block(256);
    rect_upsample_kernel<<<grid, block, 0, stream>>>(
        x, orog, wmap, bias_low, bias_high, bias_orog, cls_ids, nb, out);
}

// Round 2
// 37.845 us; speedup vs baseline: 2.0943x; 2.0943x over previous
//
#include <hip/hip_runtime.h>

#define BSZ    64
#define NF     4
#define NCLS   4
#define PLO    256
#define PHI    16384
#define KN     9
#define W27    (KN * 3)          // 27 floats per (f,p)
#define SPLITS 4

__global__ __launch_bounds__(256, 2) void rect_up_cls_kernel(
    const float* __restrict__ x,         // (B, NF*PLO)
    const float* __restrict__ orog,      // (B, PHI, 2)
    const float* __restrict__ wmap,      // (NCLS, NF, PHI, KN, 3)
    const float* __restrict__ bias_low,  // (NCLS, NF, PLO)
    const float* __restrict__ bias_high, // (NCLS, NF, PHI)
    const float* __restrict__ bias_orog, // (NCLS, 2, PHI)
    const int*   __restrict__ cls_ids,   // (B,)
    const int*   __restrict__ nb,        // (PHI, KN)
    float* __restrict__ out)             // (B, NF, PHI)
{
    __shared__ float wstage[PLO * W27];  // 27648 B, prologue only
    __shared__ float ylow[NF * PLO];     // 4096 B

    const int bid   = blockIdx.x;
    const int cls   = bid & (NCLS - 1);
    const int chunk = (bid >> 2) & 63;
    const int split = bid >> 8;          // 0..SPLITS-1
    const int t     = threadIdx.x;
    const int p     = chunk * 256 + t;   // this thread's high-res pixel

    // ---- prologue: batch-invariant state -------------------------------
    int nbr[KN], lowi[KN];
    #pragma unroll
    for (int k = 0; k < KN; ++k) {
        const int n = nb[p * KN + k];
        nbr[k]  = n;
        lowi[k] = (((n >> 7) >> 3) << 4) | ((n & 127) >> 3);
    }

    // bias_orog gathers (discarded after folding into accInit)
    float yob0[KN], yob1[KN];
    #pragma unroll
    for (int k = 0; k < KN; ++k) {
        yob0[k] = bias_orog[(cls * 2 + 0) * PHI + nbr[k]];
        yob1[k] = bias_orog[(cls * 2 + 1) * PHI + nbr[k]];
    }

    // weights: coalesced float4 global->LDS, then per-thread LDS->regs
    float w[NF][W27];
    #pragma unroll
    for (int f = 0; f < NF; ++f) {
        const float4* src = reinterpret_cast<const float4*>(
            wmap + (size_t)((cls * NF + f) * PHI + chunk * 256) * W27);
        float4* dst = reinterpret_cast<float4*>(wstage);
        __syncthreads();                       // wstage reuse guard
        #pragma unroll
        for (int i = 0; i < 7; ++i) {
            const int idx = t + i * 256;       // 1728 float4 total
            if (idx < (PLO * W27) / 4) dst[idx] = src[idx];
        }
        __syncthreads();
        #pragma unroll
        for (int q = 0; q < W27; ++q) w[f][q] = wstage[t * W27 + q];
    }

    // bias_low for this thread's low-res cell column (ylow staging uses t)
    float bl[NF];
    #pragma unroll
    for (int f = 0; f < NF; ++f) bl[f] = bias_low[(cls * NF + f) * PLO + t];

    // fold bias_high - sum_k(yob0*w1 + yob1*w2) into accumulator init
    float accInit[NF];
    #pragma unroll
    for (int f = 0; f < NF; ++f) {
        float a = bias_high[(cls * NF + f) * PHI + p];
        #pragma unroll
        for (int k = 0; k < KN; ++k)
            a -= yob0[k] * w[f][k * 3 + 1] + yob1[k] * w[f][k * 3 + 2];
        accInit[f] = a;
    }

    // ---- batch loop: only batches of my class, strided by split --------
    for (int b = split; b < BSZ; b += SPLITS) {
        if (cls_ids[b] != cls) continue;       // uniform branch

        __syncthreads();                       // ylow reuse guard
        #pragma unroll
        for (int f = 0; f < NF; ++f)
            ylow[f * PLO + t] = x[b * (NF * PLO) + f * PLO + t] - bl[f];
        __syncthreads();

        float o0[KN], o1[KN];
        #pragma unroll
        for (int k = 0; k < KN; ++k) {
            const float2 o = *reinterpret_cast<const float2*>(
                &orog[((size_t)b * PHI + nbr[k]) * 2]);
            o0[k] = o.x;
            o1[k] = o.y;
        }

        #pragma unroll
        for (int f = 0; f < NF; ++f) {
            float acc = accInit[f];
            #pragma unroll
            for (int k = 0; k < KN; ++k) {
                acc += ylow[f * PLO + lowi[k]] * w[f][k * 3 + 0]
                     + o0[k]                   * w[f][k * 3 + 1]
                     + o1[k]                   * w[f][k * 3 + 2];
            }
            out[((size_t)b * NF + f) * PHI + p] = acc;
        }
    }
}

extern "C" void kernel_launch(void* const* d_in, const int* in_sizes, int n_in,
                              void* d_out, int out_size, void* d_ws, size_t ws_size,
                              hipStream_t stream) {
    const float* x         = (const float*)d_in[0];
    const float* orog      = (const float*)d_in[1];
    const float* wmap      = (const float*)d_in[2];
    const float* bias_low  = (const float*)d_in[3];
    const float* bias_high = (const float*)d_in[4];
    const float* bias_orog = (const float*)d_in[5];
    const int*   cls_ids   = (const int*)d_in[6];
    const int*   nb        = (const int*)d_in[7];
    float* out = (float*)d_out;

    // grid: NCLS classes x 64 p-chunks x SPLITS batch-splits
    dim3 grid(NCLS * (PHI / 256) * SPLITS);
    dim3 block(256);
    rect_up_cls_kernel<<<grid, block, 0, stream>>>(
        x, orog, wmap, bias_low, bias_high, bias_orog, cls_ids, nb, out);
}

// Round 3
// 30.034 us; speedup vs baseline: 2.6390x; 1.2601x over previous
//
#include <hip/hip_runtime.h>

#define BSZ    64
#define NF     4
#define NCLS   4
#define PLO    256
#define PHI    16384
#define KN     9
#define W27    27
#define SPLITS 3

__global__ __launch_bounds__(256, 3) void rect_up_kernel(
    const float* __restrict__ x,         // (B, NF*PLO)
    const float* __restrict__ orog,      // (B, PHI, 2)
    const float* __restrict__ wmap,      // (NCLS, NF, PHI, KN, 3)
    const float* __restrict__ bias_low,  // (NCLS, NF, PLO)
    const float* __restrict__ bias_high, // (NCLS, NF, PHI)
    const float* __restrict__ bias_orog, // (NCLS, 2, PHI)
    const int*   __restrict__ cls_ids,   // (B,)
    const int*   __restrict__ nb,        // (PHI, KN)
    float* __restrict__ out)             // (B, NF, PHI)
{
    __shared__ float wstage[PLO * W27];  // 27648 B, prologue staging only

    const int bid   = blockIdx.x;
    const int cls   = bid & (NCLS - 1);
    const int chunk = (bid >> 2) & 63;
    const int split = bid >> 8;          // 0..SPLITS-1
    const int t     = threadIdx.x;
    const int p     = chunk * 256 + t;
    const int lane  = t & 63;

    // ---- class membership mask: wave has exactly BSZ=64 lanes ----------
    const unsigned long long cmask = __ballot(cls_ids[lane] == cls);

    // ---- batch-invariant neighbor geometry -----------------------------
    const int pi = p >> 7, pj = p & 127;
    const int cr0 = (pi - 2 < 0 ? 0 : pi - 2) >> 3;
    const int cr1 = (pi + 2 > 127 ? 127 : pi + 2) >> 3;
    const int cc0 = (pj - 2 < 0 ? 0 : pj - 2) >> 3;
    const int cc1 = (pj + 2 > 127 ? 127 : pj + 2) >> 3;
    int cells[4];
    cells[0] = cr0 * 16 + cc0;  cells[1] = cr0 * 16 + cc1;
    cells[2] = cr1 * 16 + cc0;  cells[3] = cr1 * 16 + cc1;

    int nbOff[KN];   // byte offset of neighbor inside one batch's orog
    int sel[KN];     // which of the 4 cells this neighbor maps to
    float yob0[KN], yob1[KN];
    #pragma unroll
    for (int k = 0; k < KN; ++k) {
        const int n = nb[p * KN + k];
        nbOff[k] = n * 8;
        sel[k] = (((n >> 7) >> 3) != cr0 ? 2 : 0) | (((n & 127) >> 3) != cc0 ? 1 : 0);
        yob0[k] = bias_orog[(cls * 2 + 0) * PHI + n];
        yob1[k] = bias_orog[(cls * 2 + 1) * PHI + n];
    }

    // ---- weights: coalesced float4 -> LDS -> regs, collapse y-weights --
    float wcy[NF][4], w1[NF][KN], w2[NF][KN];
    #pragma unroll
    for (int f = 0; f < NF; ++f) {
        __syncthreads();
        const float4* src = reinterpret_cast<const float4*>(
            wmap + (size_t)((cls * NF + f) * PHI + chunk * 256) * W27);
        float4* dst = reinterpret_cast<float4*>(wstage);
        #pragma unroll
        for (int i2 = 0; i2 < 7; ++i2) {
            const int idx = t + i2 * 256;                 // 1728 float4 total
            if (idx < (PLO * W27) / 4) dst[idx] = src[idx];
        }
        __syncthreads();
        #pragma unroll
        for (int j = 0; j < 4; ++j) wcy[f][j] = 0.0f;
        #pragma unroll
        for (int k = 0; k < KN; ++k) {
            const float w0 = wstage[t * W27 + 3 * k];
            w1[f][k] = wstage[t * W27 + 3 * k + 1];
            w2[f][k] = wstage[t * W27 + 3 * k + 2];
            #pragma unroll
            for (int j = 0; j < 4; ++j)
                wcy[f][j] += (sel[k] == j) ? w0 : 0.0f;
        }
    }

    // ---- fold bias_high - bias_orog-term - bias_low-term ---------------
    float accInit[NF];
    #pragma unroll
    for (int f = 0; f < NF; ++f) {
        float a = bias_high[(cls * NF + f) * PHI + p];
        #pragma unroll
        for (int k = 0; k < KN; ++k)
            a -= yob0[k] * w1[f][k] + yob1[k] * w2[f][k];
        #pragma unroll
        for (int j = 0; j < 4; ++j)
            a -= bias_low[(cls * NF + f) * PLO + cells[j]] * wcy[f][j];
        accInit[f] = a;
    }

    // ---- scan state: take every SPLITS-th matching batch ---------------
    unsigned long long m = cmask;
    int ord = 0;
    auto nextb = [&]() -> int {
        while (m) {
            const int b = __ffsll((unsigned long long)m) - 1;
            m &= m - 1;
            const bool take = (ord == split);
            ord = (ord + 1 == SPLITS) ? 0 : ord + 1;
            if (take) return b;
        }
        return -1;
    };

    int b = nextb();
    if (b < 0) return;

    float o0[KN], o1[KN];
    {
        const char* ob = (const char*)orog + (size_t)b * (PHI * 2 * 4);
        #pragma unroll
        for (int k = 0; k < KN; ++k) {
            const float2 v = *reinterpret_cast<const float2*>(ob + nbOff[k]);
            o0[k] = v.x; o1[k] = v.y;
        }
    }

    // ---- batch loop: no barriers, orog prefetched one batch ahead ------
    while (true) {
        const int bn = nextb();
        float n0[KN], n1[KN];
        if (bn >= 0) {
            const char* ob = (const char*)orog + (size_t)bn * (PHI * 2 * 4);
            #pragma unroll
            for (int k = 0; k < KN; ++k) {
                const float2 v = *reinterpret_cast<const float2*>(ob + nbOff[k]);
                n0[k] = v.x; n1[k] = v.y;
            }
        }

        const float* xb = x + b * (NF * PLO);
        #pragma unroll
        for (int f = 0; f < NF; ++f) {
            float acc = accInit[f];
            #pragma unroll
            for (int j = 0; j < 4; ++j)
                acc += xb[f * PLO + cells[j]] * wcy[f][j];
            #pragma unroll
            for (int k = 0; k < KN; ++k)
                acc += o0[k] * w1[f][k] + o1[k] * w2[f][k];
            out[((size_t)b * NF + f) * PHI + p] = acc;
        }

        if (bn < 0) break;
        b = bn;
        #pragma unroll
        for (int k = 0; k < KN; ++k) { o0[k] = n0[k]; o1[k] = n1[k]; }
    }
}

extern "C" void kernel_launch(void* const* d_in, const int* in_sizes, int n_in,
                              void* d_out, int out_size, void* d_ws, size_t ws_size,
                              hipStream_t stream) {
    const float* x         = (const float*)d_in[0];
    const float* orog      = (const float*)d_in[1];
    const float* wmap      = (const float*)d_in[2];
    const float* bias_low  = (const float*)d_in[3];
    const float* bias_high = (const float*)d_in[4];
    const float* bias_orog = (const float*)d_in[5];
    const int*   cls_ids   = (const int*)d_in[6];
    const int*   nb        = (const int*)d_in[7];
    float* out = (float*)d_out;

    // grid: NCLS classes x 64 p-chunks x SPLITS batch-splits = 768 blocks
    dim3 grid(NCLS * (PHI / 256) * SPLITS);
    dim3 block(256);
    rect_up_kernel<<<grid, block, 0, stream>>>(
        x, orog, wmap, bias_low, bias_high, bias_orog, cls_ids, nb, out);
}